// Round 6
// baseline (865.513 us; speedup 1.0000x reference)
//
#include <hip/hip_runtime.h>
#include <stdint.h>

typedef uint16_t u16;
typedef __bf16 bf16x8 __attribute__((ext_vector_type(8)));
typedef float f32x4 __attribute__((ext_vector_type(4)));

__device__ __forceinline__ float bf2f(u16 u) {
  union { uint32_t i; float f; } v; v.i = ((uint32_t)u) << 16; return v.f;
}
__device__ __forceinline__ u16 f2bf(float f) {
  union { float f; uint32_t i; } v; v.f = f;
  uint32_t r = v.i + 0x7fffu + ((v.i >> 16) & 1u);
  return (u16)(r >> 16);
}
__device__ __forceinline__ uint32_t pack2(float a, float b) {
  return (uint32_t)f2bf(a) | ((uint32_t)f2bf(b) << 16);
}
// async global->LDS, 16B per lane; LDS dest must be wave-uniform base + lane*16
__device__ __forceinline__ void gll16(const u16* g, u16* l) {
  __builtin_amdgcn_global_load_lds((const __attribute__((address_space(1))) void*)g,
                                   (__attribute__((address_space(3))) void*)l, 16, 0, 0);
}

// ---------------- fp32 -> bf16 bulk convert ----------------
__global__ __launch_bounds__(256) void f32_to_bf16(
    const float* __restrict__ in, u16* __restrict__ out)
{
  int idx = blockIdx.x * 256 + threadIdx.x;
  float4 v = *(const float4*)(in + (size_t)idx * 4);
  uint2 o;
  o.x = pack2(v.x, v.y);
  o.y = pack2(v.z, v.w);
  *(uint2*)(out + (size_t)idx * 4) = o;
}

// ---------------- concat 3 fp32 bias vectors -> one 3072 fp32 ----------------
__global__ __launch_bounds__(256) void concat_bias(
    const float* __restrict__ a, const float* __restrict__ b,
    const float* __restrict__ c, float* __restrict__ o)
{
  int i = blockIdx.x * 256 + threadIdx.x;  // 0..3071
  float v = (i < 1024) ? a[i] : ((i < 2048) ? b[i - 1024] : c[i - 2048]);
  o[i] = v;
}

// ------- weight transpose + fp32->bf16 convert (R x C fp32 -> C x R bf16) -------
__global__ __launch_bounds__(256) void transpose_f2b(
    const float* __restrict__ in, u16* __restrict__ out, int R, int C, int ldo)
{
  __shared__ u16 tile[32][33];
  int c0 = blockIdx.x * 32, r0 = blockIdx.y * 32;
  int x = threadIdx.x, y = threadIdx.y;  // 32 x 8
#pragma unroll
  for (int i = 0; i < 32; i += 8)
    tile[y + i][x] = f2bf(in[(size_t)(r0 + y + i) * C + (c0 + x)]);
  __syncthreads();
#pragma unroll
  for (int i = 0; i < 32; i += 8)
    out[(size_t)(c0 + y + i) * ldo + (r0 + x)] = tile[x][y + i];
}

// ------- V transpose: QKV V-slice [8192][64 per head, stride 3072] ->
//         Vtg[bh][d][spos], spos = sigma(key) within each 64-key chunk,
//         sigma(key) = ((key&15)<<2) | (key>>4)  (matches flash P layout) -------
__global__ __launch_bounds__(256) void transpose_v(
    const u16* __restrict__ src, u16* __restrict__ dst)
{
  __shared__ u16 tile[64][72];
  int kc = blockIdx.x;      // key chunk (64 keys)
  int bh = blockIdx.y;      // b*16+h
  int b = bh >> 4, h = bh & 15;
  int t = threadIdx.x;
  int r = t >> 3;           // 0..31
  int c0 = (t & 7) * 8;     // 0..56
  const u16* s0 = src + ((size_t)(b * 2048 + kc * 64 + r) * 3072) + h * 64 + c0;
#pragma unroll
  for (int hh = 0; hh < 2; hh++)
    *(uint4*)(&tile[r + hh * 32][c0]) = *(const uint4*)(s0 + (size_t)hh * 32 * 3072);
  __syncthreads();
#pragma unroll
  for (int hh = 0; hh < 2; hh++) {
    int d = r + hh * 32;
    u16 vals[8];
#pragma unroll
    for (int p = 0; p < 8; p++) {
      int pos = c0 + p;
      int key = ((pos & 3) << 4) | ((pos >> 2) & 15);  // sigma^-1
      vals[p] = tile[key][d];
    }
    *(uint4*)(dst + ((size_t)bh * 64 + d) * 2048 + (size_t)kc * 64 + c0) = *(uint4*)vals;
  }
}

// ------- GEMM: C[MxN] = A[MxK(lda)] @ BT[NxK(ldb)]^T (+bias)(+C)(relu) -------
// BK=64, async gll16 staging with XOR-block swizzle:
//   physical 16B-block b' = b ^ (row & 7); applied on global source address.
#define BM 128
#define BN 128
#define BK 64

__global__ __launch_bounds__(256, 2) void gemm_bt(
    const u16* __restrict__ A, const u16* __restrict__ BT,
    const float* __restrict__ bias, u16* __restrict__ C,
    int N, int K, int lda, int ldb, int ldc, int relu, int addC)
{
  __shared__ __align__(16) u16 As[BM][BK];   // 16 KB
  __shared__ __align__(16) u16 Bs[BN][BK];   // 16 KB
  int tid = threadIdx.x;
  int m0 = blockIdx.y * BM, n0 = blockIdx.x * BN;
  int wave = tid >> 6, lane = tid & 63;
  int quad = lane >> 4, tr = lane & 15;
  int wm = (wave >> 1) * 64, wn = (wave & 1) * 64;
  int tr7 = tr & 7;

  f32x4 zero = {0.f, 0.f, 0.f, 0.f};
  f32x4 acc[4][4];
#pragma unroll
  for (int i = 0; i < 4; i++)
#pragma unroll
    for (int j = 0; j < 4; j++) acc[i][j] = zero;

  int srow = tid >> 3;                      // 0..31
  int sblk = (tid & 7) ^ (srow & 7);        // swizzled source 16B-block
  const u16* Abase = A  + (size_t)(m0 + srow) * lda + sblk * 8;
  const u16* Bbase = BT + (size_t)(n0 + srow) * ldb + sblk * 8;
  u16* la = &As[0][0] + tid * 8;
  u16* lb = &Bs[0][0] + tid * 8;

  for (int k0 = 0; k0 < K; k0 += BK) {
#pragma unroll
    for (int R = 0; R < 4; R++) {
      gll16(Abase + (size_t)(R * 32) * lda + k0, la + R * 2048);
      gll16(Bbase + (size_t)(R * 32) * ldb + k0, lb + R * 2048);
    }
    __syncthreads();
#pragma unroll
    for (int ks = 0; ks < 2; ks++) {
      bf16x8 af[4], bfr[4];
#pragma unroll
      for (int i = 0; i < 4; i++)
        af[i]  = *(const bf16x8*)(&As[wm + i*16 + tr][(((ks*4 + quad) ^ tr7)) * 8]);
#pragma unroll
      for (int j = 0; j < 4; j++)
        bfr[j] = *(const bf16x8*)(&Bs[wn + j*16 + tr][(((ks*4 + quad) ^ tr7)) * 8]);
#pragma unroll
      for (int i = 0; i < 4; i++)
#pragma unroll
        for (int j = 0; j < 4; j++)
          acc[i][j] = __builtin_amdgcn_mfma_f32_16x16x32_bf16(af[i], bfr[j], acc[i][j], 0, 0, 0);
    }
    __syncthreads();
  }

#pragma unroll
  for (int j = 0; j < 4; j++) {
    int n = n0 + wn + j*16 + tr;
    float bv = bias ? bias[n] : 0.f;
#pragma unroll
    for (int i = 0; i < 4; i++) {
      int mrow = m0 + wm + i*16 + quad*4;
#pragma unroll
      for (int r = 0; r < 4; r++) {
        size_t idx = (size_t)(mrow + r) * ldc + n;
        float v = acc[i][j][r] + bv;
        if (addC) v += bf2f(C[idx]);
        if (relu) v = v > 0.f ? v : 0.f;
        C[idx] = f2bf(v);
      }
    }
  }
}

// ---------------- flash attention v5 ----------------
// block 512 (8 waves), 32 q-rows/wave; grid (S/256, B*H).
// K staged via gll16 into unpadded Ks[64][64] with XOR-block swizzle
// (block' = block ^ (row&7), applied on global source address).
// V from pre-transposed+sigma-permuted Vtg[bh][d][key], staged the same way.
// Fixed-max softmax (scores bounded), deferred l-reduction.
// P: Ps[wave][q][pos] stride 72, pos = sigma(key); b64 writes, b128 reads.
__global__ __launch_bounds__(512, 6) void flash_attn(
    const u16* __restrict__ Qb, const u16* __restrict__ Kb,
    const u16* __restrict__ Vtg, u16* __restrict__ Ob, int ldqkv, int ldo)
{
  __shared__ __align__(16) u16 Ks[64][64];     // 8 KB
  __shared__ __align__(16) u16 Vt[64][64];     // 8 KB
  __shared__ __align__(16) u16 Ps[8][32][72];  // 36 KB   (total 52 KB -> 3 blocks/CU)

  const int S = 2048;
  int tid = threadIdx.x;
  int wv = tid >> 6, lane = tid & 63;
  int quad = lane >> 4, tr = lane & 15;
  int tr7 = tr & 7;
  int bh = blockIdx.y;
  int b = bh >> 4, h = bh & 15;
  int q0 = blockIdx.x * 256;
  int wq = wv * 32;
  size_t rowbase = (size_t)b * S;
  int colbase = h * 64;

  // Q fragments: A[m=tr][k=quad*8+j]
  bf16x8 qf[2][2];
#pragma unroll
  for (int i = 0; i < 2; i++)
#pragma unroll
    for (int ks = 0; ks < 2; ks++)
      qf[i][ks] = *(const bf16x8*)(Qb + (rowbase + q0 + wq + i*16 + tr) * ldqkv
                                   + colbase + ks*32 + quad*8);

  f32x4 zero = {0.f, 0.f, 0.f, 0.f};
  f32x4 o[2][4];
  float lsum[2][4];
#pragma unroll
  for (int i = 0; i < 2; i++)
#pragma unroll
    for (int r = 0; r < 4; r++) lsum[i][r] = 0.f;
#pragma unroll
  for (int i = 0; i < 2; i++)
#pragma unroll
    for (int j = 0; j < 4; j++) o[i][j] = zero;

  const float sc = 0.125f;  // 1/sqrt(64)

  int srow = tid >> 3;                      // 0..63
  int sblk = (tid & 7) ^ (srow & 7);        // swizzled source 16B-block
  const u16* kgbase = Kb + (rowbase + srow) * ldqkv + colbase + sblk * 8;
  const u16* vgbase = Vtg + ((size_t)bh * 64 + srow) * 2048 + sblk * 8;
  u16* kl = &Ks[0][0] + tid * 8;
  u16* vl = &Vt[0][0] + tid * 8;

  for (int kv0 = 0; kv0 < S; kv0 += 64) {
    gll16(kgbase + (size_t)kv0 * ldqkv, kl);
    gll16(vgbase + kv0, vl);
    __syncthreads();

    // S = Q K^T
    f32x4 s[2][4];
#pragma unroll
    for (int i = 0; i < 2; i++)
#pragma unroll
      for (int j = 0; j < 4; j++) s[i][j] = zero;
#pragma unroll
    for (int ks = 0; ks < 2; ks++) {
      bf16x8 kf[4];
#pragma unroll
      for (int j = 0; j < 4; j++)
        kf[j] = *(const bf16x8*)(&Ks[j*16 + tr][((ks*4 + quad) ^ tr7) * 8]);
#pragma unroll
      for (int i = 0; i < 2; i++)
#pragma unroll
        for (int j = 0; j < 4; j++)
          s[i][j] = __builtin_amdgcn_mfma_f32_16x16x32_bf16(qf[i][ks], kf[j], s[i][j], 0, 0, 0);
    }

    // fixed-max softmax: p = exp(score/8); partial l per lane; P -> LDS (b64)
#pragma unroll
    for (int i = 0; i < 2; i++) {
#pragma unroll
      for (int r = 0; r < 4; r++) {
        float p0 = __expf(s[i][0][r] * sc);
        float p1 = __expf(s[i][1][r] * sc);
        float p2 = __expf(s[i][2][r] * sc);
        float p3 = __expf(s[i][3][r] * sc);
        lsum[i][r] += (p0 + p1) + (p2 + p3);
        uint2 w;
        w.x = (__float_as_uint(p0) >> 16) | (__float_as_uint(p1) & 0xffff0000u);
        w.y = (__float_as_uint(p2) >> 16) | (__float_as_uint(p3) & 0xffff0000u);
        *(uint2*)(&Ps[wv][i*16 + quad*4 + r][tr*4]) = w;
      }
    }

    // O += P @ V  (both operands in sigma-permuted key order -> consistent)
#pragma unroll
    for (int ks = 0; ks < 2; ks++) {
      bf16x8 pf[2];
#pragma unroll
      for (int i = 0; i < 2; i++)
        pf[i] = *(const bf16x8*)(&Ps[wv][i*16 + tr][ks*32 + quad*8]);
#pragma unroll
      for (int jd = 0; jd < 4; jd++) {
        bf16x8 vf = *(const bf16x8*)(&Vt[jd*16 + tr][((ks*4 + quad) ^ tr7) * 8]);
#pragma unroll
        for (int i = 0; i < 2; i++)
          o[i][jd] = __builtin_amdgcn_mfma_f32_16x16x32_bf16(pf[i], vf, o[i][jd], 0, 0, 0);
      }
    }
    __syncthreads();
  }

  // finalize: reduce l across the 16 tr lanes, scale, store
#pragma unroll
  for (int i = 0; i < 2; i++) {
#pragma unroll
    for (int r = 0; r < 4; r++) {
      float l = lsum[i][r];
      l += __shfl_xor(l, 1, 64);
      l += __shfl_xor(l, 2, 64);
      l += __shfl_xor(l, 4, 64);
      l += __shfl_xor(l, 8, 64);
      float inv = 1.f / l;
      size_t qrow = rowbase + q0 + wq + i*16 + quad*4 + r;
#pragma unroll
      for (int jd = 0; jd < 4; jd++)
        Ob[qrow * ldo + colbase + jd*16 + tr] = f2bf(o[i][jd][r] * inv);
    }
  }
}

// ---- fused residual-add + LayerNorm, variant A: X fp32 + R bf16 -> Y bf16 ----
__global__ __launch_bounds__(256) void add_ln_a(
    const float* __restrict__ X, const u16* __restrict__ Rr,
    const float* __restrict__ G, const float* __restrict__ Bb,
    u16* __restrict__ Y)
{
  int row = blockIdx.x;
  int tid = threadIdx.x;
  __shared__ float sbuf[4], qbuf[4];
  float4 xv = *(const float4*)(X + (size_t)row * 1024 + tid * 4);
  uint2 ru = *(const uint2*)(Rr + (size_t)row * 1024 + tid * 4);
  const u16* rs = (const u16*)&ru;
  const float* xs = (const float*)&xv;
  float v[4];
  float s = 0.f, q = 0.f;
#pragma unroll
  for (int e = 0; e < 4; e++) {
    float a = xs[e] + bf2f(rs[e]);
    v[e] = a; s += a; q += a * a;
  }
#pragma unroll
  for (int off = 1; off < 64; off <<= 1) {
    s += __shfl_xor(s, off, 64);
    q += __shfl_xor(q, off, 64);
  }
  if ((tid & 63) == 0) { sbuf[tid >> 6] = s; qbuf[tid >> 6] = q; }
  __syncthreads();
  s = sbuf[0] + sbuf[1] + sbuf[2] + sbuf[3];
  q = qbuf[0] + qbuf[1] + qbuf[2] + qbuf[3];
  float mu  = s * (1.f / 1024.f);
  float var = q * (1.f / 1024.f) - mu * mu;
  float inv = rsqrtf(var + 1e-5f);
#pragma unroll
  for (int e = 0; e < 4; e++) {
    int col = tid * 4 + e;
    float yv = (v[e] - mu) * inv * G[col] + Bb[col];
    Y[(size_t)row * 1024 + col] = f2bf(yv);
  }
}

// ---- variant B: X bf16 + R bf16 -> Y fp32 (final output) ----
__global__ __launch_bounds__(256) void add_ln_b(
    const u16* __restrict__ X, const u16* __restrict__ Rr,
    const float* __restrict__ G, const float* __restrict__ Bb,
    float* __restrict__ Y)
{
  int row = blockIdx.x;
  int tid = threadIdx.x;
  __shared__ float sbuf[4], qbuf[4];
  uint2 xu = *(const uint2*)(X  + (size_t)row * 1024 + tid * 4);
  uint2 ru = *(const uint2*)(Rr + (size_t)row * 1024 + tid * 4);
  const u16* xs = (const u16*)&xu;
  const u16* rs = (const u16*)&ru;
  float v[4];
  float s = 0.f, q = 0.f;
#pragma unroll
  for (int e = 0; e < 4; e++) {
    float a = bf2f(xs[e]) + bf2f(rs[e]);
    v[e] = a; s += a; q += a * a;
  }
#pragma unroll
  for (int off = 1; off < 64; off <<= 1) {
    s += __shfl_xor(s, off, 64);
    q += __shfl_xor(q, off, 64);
  }
  if ((tid & 63) == 0) { sbuf[tid >> 6] = s; qbuf[tid >> 6] = q; }
  __syncthreads();
  s = sbuf[0] + sbuf[1] + sbuf[2] + sbuf[3];
  q = qbuf[0] + qbuf[1] + qbuf[2] + qbuf[3];
  float mu  = s * (1.f / 1024.f);
  float var = q * (1.f / 1024.f) - mu * mu;
  float inv = rsqrtf(var + 1e-5f);
  float4 yv;
  float* yp = (float*)&yv;
#pragma unroll
  for (int e = 0; e < 4; e++) {
    int col = tid * 4 + e;
    yp[e] = (v[e] - mu) * inv * G[col] + Bb[col];
  }
  *(float4*)(Y + (size_t)row * 1024 + tid * 4) = yv;
}

extern "C" void kernel_launch(void* const* d_in, const int* in_sizes, int n_in,
                              void* d_out, int out_size, void* d_ws, size_t ws_size,
                              hipStream_t stream) {
  const float* x   = (const float*)d_in[0];
  const float* Wq  = (const float*)d_in[1];
  const float* bq  = (const float*)d_in[2];
  const float* Wk  = (const float*)d_in[3];
  const float* bk  = (const float*)d_in[4];
  const float* Wv  = (const float*)d_in[5];
  const float* bv  = (const float*)d_in[6];
  const float* Wo  = (const float*)d_in[7];
  const float* bo  = (const float*)d_in[8];
  const float* W1  = (const float*)d_in[9];
  const float* b1  = (const float*)d_in[10];
  const float* W2  = (const float*)d_in[11];
  const float* b2  = (const float*)d_in[12];
  const float* g1  = (const float*)d_in[13];
  const float* be1 = (const float*)d_in[14];
  const float* g2  = (const float*)d_in[15];
  const float* be2 = (const float*)d_in[16];
  float* out = (float*)d_out;
  u16* ws  = (u16*)d_ws;

  const int Nrow = 8192, E = 1024, FFd = 4096;
  const size_t M1 = 1048576;
  // workspace (44M u16 = 88 MB peak, proven safe):
  //  [0,8M):   xb -> (after QKV gemm) Vtg -> (after flash) X1
  //  [8,11M):  WqkvT [3072][1024]
  //  [11,12M): WoT
  //  [12,16M): W1T [4096][1024]
  //  [16,20M): W2T [1024][4096]
  //  [20,44M): QKV [8192][3072]; V-slice becomes ctx; region reused as F2
  // d_out (32 MB) doubles as scratch: bqkv fp32 -> AO (u16) -> Hc (u16) -> final fp32
  u16* xb     = ws;
  u16* WqkvT  = ws + 8  * M1;
  u16* WoT    = ws + 11 * M1;
  u16* W1T    = ws + 12 * M1;
  u16* W2T    = ws + 16 * M1;
  u16* QKV    = ws + 20 * M1;
  u16* Vtg    = ws;               // over xb (dead after QKV gemm)
  u16* X1     = ws;               // over Vtg (dead after flash)
  u16* F2     = ws + 20 * M1;     // over QKV (dead after Wo gemm)
  float* bqkv = (float*)d_out;
  u16*  AO    = (u16*)d_out;
  u16*  Hc    = (u16*)d_out;

  dim3 tb(256);
  dim3 tt(32, 8);
  f32_to_bf16<<<dim3(8192), tb, 0, stream>>>(x, xb);
  transpose_f2b<<<dim3(E/32,  E/32),  tt, 0, stream>>>(Wq, WqkvT,        E,   E,   E);
  transpose_f2b<<<dim3(E/32,  E/32),  tt, 0, stream>>>(Wk, WqkvT + 1*M1, E,   E,   E);
  transpose_f2b<<<dim3(E/32,  E/32),  tt, 0, stream>>>(Wv, WqkvT + 2*M1, E,   E,   E);
  transpose_f2b<<<dim3(E/32,  E/32),  tt, 0, stream>>>(Wo, WoT,          E,   E,   E);
  transpose_f2b<<<dim3(FFd/32,E/32),  tt, 0, stream>>>(W1, W1T,          E,   FFd, E);
  transpose_f2b<<<dim3(E/32,  FFd/32),tt, 0, stream>>>(W2, W2T,          FFd, E,   FFd);
  concat_bias<<<dim3(12), tb, 0, stream>>>(bq, bk, bv, bqkv);

  // fused QKV projection: [8192,1024] @ [1024,3072] -> QKV
  gemm_bt<<<dim3(24, Nrow/BM), tb, 0, stream>>>(xb, WqkvT, bqkv, QKV,
                                                3072, E, E, E, 3072, 0, 0);
  // V -> Vtg (transposed + sigma-permuted, per bh)
  transpose_v<<<dim3(32, 64), tb, 0, stream>>>(QKV + 2048, Vtg);
  // flash: ctx written over the V-slice of QKV
  flash_attn<<<dim3(8, 64), dim3(512), 0, stream>>>(QKV, QKV + 1024, Vtg,
                                                    QKV + 2048, 3072, 3072);
  // Wo: ctx (stride 3072) @ WoT -> AO (in d_out)
  gemm_bt<<<dim3(8, Nrow/BM), tb, 0, stream>>>(QKV + 2048, WoT, bo, AO,
                                               E, E, 3072, E, E, 0, 0);
  add_ln_a<<<dim3(Nrow), tb, 0, stream>>>(x, AO, g1, be1, X1);

  // FFN in 2 chunks of 2048 (hidden lives in d_out; F2 accumulates in ws)
  for (int c = 0; c < 2; c++) {
    gemm_bt<<<dim3(16, Nrow/BM), tb, 0, stream>>>(
        X1, W1T + (size_t)c * 2048 * E, b1 + c * 2048, Hc,
        2048, E, E, E, 2048, 1, 0);
    gemm_bt<<<dim3(8, Nrow/BM), tb, 0, stream>>>(
        Hc, W2T + (size_t)c * 2048, (c == 0 ? b2 : (const float*)nullptr), F2,
        E, 2048, 2048, FFd, E, 0, (c == 0 ? 0 : 1));
  }

  add_ln_b<<<dim3(Nrow), tb, 0, stream>>>(X1, F2, g2, be2, out);
}

// Round 7
// 572.810 us; speedup vs baseline: 1.5110x; 1.5110x over previous
//
#include <hip/hip_runtime.h>
#include <stdint.h>

typedef uint16_t u16;
typedef __bf16 bf16x8 __attribute__((ext_vector_type(8)));
typedef float f32x4 __attribute__((ext_vector_type(4)));

__device__ __forceinline__ float bf2f(u16 u) {
  union { uint32_t i; float f; } v; v.i = ((uint32_t)u) << 16; return v.f;
}
__device__ __forceinline__ u16 f2bf(float f) {
  union { float f; uint32_t i; } v; v.f = f;
  uint32_t r = v.i + 0x7fffu + ((v.i >> 16) & 1u);
  return (u16)(r >> 16);
}
__device__ __forceinline__ uint32_t pack2(float a, float b) {
  return (uint32_t)f2bf(a) | ((uint32_t)f2bf(b) << 16);
}
// async global->LDS, 16B per lane; LDS dest must be wave-uniform base + lane*16
__device__ __forceinline__ void gll16(const u16* g, u16* l) {
  __builtin_amdgcn_global_load_lds((const __attribute__((address_space(1))) void*)g,
                                   (__attribute__((address_space(3))) void*)l, 16, 0, 0);
}

// ---------------- fp32 -> bf16 bulk convert ----------------
__global__ __launch_bounds__(256) void f32_to_bf16(
    const float* __restrict__ in, u16* __restrict__ out)
{
  int idx = blockIdx.x * 256 + threadIdx.x;
  float4 v = *(const float4*)(in + (size_t)idx * 4);
  uint2 o;
  o.x = pack2(v.x, v.y);
  o.y = pack2(v.z, v.w);
  *(uint2*)(out + (size_t)idx * 4) = o;
}

// ---------------- concat 3 fp32 bias vectors -> one 3072 fp32 ----------------
__global__ __launch_bounds__(256) void concat_bias(
    const float* __restrict__ a, const float* __restrict__ b,
    const float* __restrict__ c, float* __restrict__ o)
{
  int i = blockIdx.x * 256 + threadIdx.x;  // 0..3071
  float v = (i < 1024) ? a[i] : ((i < 2048) ? b[i - 1024] : c[i - 2048]);
  o[i] = v;
}

// ------- weight transpose + fp32->bf16 convert (R x C fp32 -> C x R bf16) -------
__global__ __launch_bounds__(256) void transpose_f2b(
    const float* __restrict__ in, u16* __restrict__ out, int R, int C, int ldo)
{
  __shared__ u16 tile[32][33];
  int c0 = blockIdx.x * 32, r0 = blockIdx.y * 32;
  int x = threadIdx.x, y = threadIdx.y;  // 32 x 8
#pragma unroll
  for (int i = 0; i < 32; i += 8)
    tile[y + i][x] = f2bf(in[(size_t)(r0 + y + i) * C + (c0 + x)]);
  __syncthreads();
#pragma unroll
  for (int i = 0; i < 32; i += 8)
    out[(size_t)(c0 + y + i) * ldo + (r0 + x)] = tile[x][y + i];
}

// ------- V transpose: QKV V-slice [8192][64 per head, stride 3072] ->
//         Vtg[bh][d][spos], spos = sigma(key) within each 64-key chunk,
//         sigma(key) = ((key&15)<<2) | (key>>4)  (matches flash P layout) -------
__global__ __launch_bounds__(256) void transpose_v(
    const u16* __restrict__ src, u16* __restrict__ dst)
{
  __shared__ u16 tile[64][72];
  int kc = blockIdx.x;      // key chunk (64 keys)
  int bh = blockIdx.y;      // b*16+h
  int b = bh >> 4, h = bh & 15;
  int t = threadIdx.x;
  int r = t >> 3;           // 0..31
  int c0 = (t & 7) * 8;     // 0..56
  const u16* s0 = src + ((size_t)(b * 2048 + kc * 64 + r) * 3072) + h * 64 + c0;
#pragma unroll
  for (int hh = 0; hh < 2; hh++)
    *(uint4*)(&tile[r + hh * 32][c0]) = *(const uint4*)(s0 + (size_t)hh * 32 * 3072);
  __syncthreads();
#pragma unroll
  for (int hh = 0; hh < 2; hh++) {
    int d = r + hh * 32;
    u16 vals[8];
#pragma unroll
    for (int p = 0; p < 8; p++) {
      int pos = c0 + p;
      int key = ((pos & 3) << 4) | ((pos >> 2) & 15);  // sigma^-1
      vals[p] = tile[key][d];
    }
    *(uint4*)(dst + ((size_t)bh * 64 + d) * 2048 + (size_t)kc * 64 + c0) = *(uint4*)vals;
  }
}

// ------- GEMM: C[MxN] = A[MxK(lda)] @ BT[NxK(ldb)]^T (+bias)(+C)(relu) -------
// BK=64, async gll16 staging with XOR-block swizzle:
//   physical 16B-block b' = b ^ (row & 7); applied on global source address.
#define BM 128
#define BN 128
#define BK 64

__global__ __launch_bounds__(256, 2) void gemm_bt(
    const u16* __restrict__ A, const u16* __restrict__ BT,
    const float* __restrict__ bias, u16* __restrict__ C,
    int N, int K, int lda, int ldb, int ldc, int relu, int addC)
{
  __shared__ __align__(16) u16 As[BM][BK];   // 16 KB
  __shared__ __align__(16) u16 Bs[BN][BK];   // 16 KB
  int tid = threadIdx.x;
  int m0 = blockIdx.y * BM, n0 = blockIdx.x * BN;
  int wave = tid >> 6, lane = tid & 63;
  int quad = lane >> 4, tr = lane & 15;
  int wm = (wave >> 1) * 64, wn = (wave & 1) * 64;
  int tr7 = tr & 7;

  f32x4 zero = {0.f, 0.f, 0.f, 0.f};
  f32x4 acc[4][4];
#pragma unroll
  for (int i = 0; i < 4; i++)
#pragma unroll
    for (int j = 0; j < 4; j++) acc[i][j] = zero;

  int srow = tid >> 3;                      // 0..31
  int sblk = (tid & 7) ^ (srow & 7);        // swizzled source 16B-block
  const u16* Abase = A  + (size_t)(m0 + srow) * lda + sblk * 8;
  const u16* Bbase = BT + (size_t)(n0 + srow) * ldb + sblk * 8;
  u16* la = &As[0][0] + tid * 8;
  u16* lb = &Bs[0][0] + tid * 8;

  for (int k0 = 0; k0 < K; k0 += BK) {
#pragma unroll
    for (int R = 0; R < 4; R++) {
      gll16(Abase + (size_t)(R * 32) * lda + k0, la + R * 2048);
      gll16(Bbase + (size_t)(R * 32) * ldb + k0, lb + R * 2048);
    }
    __syncthreads();
#pragma unroll
    for (int ks = 0; ks < 2; ks++) {
      bf16x8 af[4], bfr[4];
#pragma unroll
      for (int i = 0; i < 4; i++)
        af[i]  = *(const bf16x8*)(&As[wm + i*16 + tr][(((ks*4 + quad) ^ tr7)) * 8]);
#pragma unroll
      for (int j = 0; j < 4; j++)
        bfr[j] = *(const bf16x8*)(&Bs[wn + j*16 + tr][(((ks*4 + quad) ^ tr7)) * 8]);
#pragma unroll
      for (int i = 0; i < 4; i++)
#pragma unroll
        for (int j = 0; j < 4; j++)
          acc[i][j] = __builtin_amdgcn_mfma_f32_16x16x32_bf16(af[i], bfr[j], acc[i][j], 0, 0, 0);
    }
    __syncthreads();
  }

#pragma unroll
  for (int j = 0; j < 4; j++) {
    int n = n0 + wn + j*16 + tr;
    float bv = bias ? bias[n] : 0.f;
#pragma unroll
    for (int i = 0; i < 4; i++) {
      int mrow = m0 + wm + i*16 + quad*4;
#pragma unroll
      for (int r = 0; r < 4; r++) {
        size_t idx = (size_t)(mrow + r) * ldc + n;
        float v = acc[i][j][r] + bv;
        if (addC) v += bf2f(C[idx]);
        if (relu) v = v > 0.f ? v : 0.f;
        C[idx] = f2bf(v);
      }
    }
  }
}

// ---------------- flash attention v6 ----------------
// block 512 (8 waves), 32 q-rows/wave; grid (S/256, B*H).
// launch_bounds (512,4): VGPR cap 128 — round 6's (512,6) capped at 85 and
// spilled the o-accumulators to scratch (910 MB HBM write traffic, 410 µs).
// LDS is 52 KB so HW can still reach 3 blocks/CU if compiler lands <=85 VGPRs.
// K staged via gll16 into unpadded Ks[64][64] with XOR-block swizzle;
// V from pre-transposed+sigma-permuted Vtg[bh][d][key], staged the same way.
// Fixed-max softmax (scores bounded), deferred l-reduction.
__global__ __launch_bounds__(512, 4) void flash_attn(
    const u16* __restrict__ Qb, const u16* __restrict__ Kb,
    const u16* __restrict__ Vtg, u16* __restrict__ Ob, int ldqkv, int ldo)
{
  __shared__ __align__(16) u16 Ks[64][64];     // 8 KB
  __shared__ __align__(16) u16 Vt[64][64];     // 8 KB
  __shared__ __align__(16) u16 Ps[8][32][72];  // 36 KB   (total 52 KB)

  const int S = 2048;
  int tid = threadIdx.x;
  int wv = tid >> 6, lane = tid & 63;
  int quad = lane >> 4, tr = lane & 15;
  int tr7 = tr & 7;
  int bh = blockIdx.y;
  int b = bh >> 4, h = bh & 15;
  int q0 = blockIdx.x * 256;
  int wq = wv * 32;
  size_t rowbase = (size_t)b * S;
  int colbase = h * 64;

  // Q fragments: A[m=tr][k=quad*8+j]
  bf16x8 qf[2][2];
#pragma unroll
  for (int i = 0; i < 2; i++)
#pragma unroll
    for (int ks = 0; ks < 2; ks++)
      qf[i][ks] = *(const bf16x8*)(Qb + (rowbase + q0 + wq + i*16 + tr) * ldqkv
                                   + colbase + ks*32 + quad*8);

  f32x4 zero = {0.f, 0.f, 0.f, 0.f};
  f32x4 o[2][4];
  float lsum[2][4];
#pragma unroll
  for (int i = 0; i < 2; i++)
#pragma unroll
    for (int r = 0; r < 4; r++) lsum[i][r] = 0.f;
#pragma unroll
  for (int i = 0; i < 2; i++)
#pragma unroll
    for (int j = 0; j < 4; j++) o[i][j] = zero;

  const float sc = 0.125f;  // 1/sqrt(64)

  int srow = tid >> 3;                      // 0..63
  int sblk = (tid & 7) ^ (srow & 7);        // swizzled source 16B-block
  const u16* kgbase = Kb + (rowbase + srow) * ldqkv + colbase + sblk * 8;
  const u16* vgbase = Vtg + ((size_t)bh * 64 + srow) * 2048 + sblk * 8;
  u16* kl = &Ks[0][0] + tid * 8;
  u16* vl = &Vt[0][0] + tid * 8;

  for (int kv0 = 0; kv0 < S; kv0 += 64) {
    gll16(kgbase + (size_t)kv0 * ldqkv, kl);
    gll16(vgbase + kv0, vl);
    __syncthreads();

    // S = Q K^T
    f32x4 s[2][4];
#pragma unroll
    for (int i = 0; i < 2; i++)
#pragma unroll
      for (int j = 0; j < 4; j++) s[i][j] = zero;
#pragma unroll
    for (int ks = 0; ks < 2; ks++) {
      bf16x8 kf[4];
#pragma unroll
      for (int j = 0; j < 4; j++)
        kf[j] = *(const bf16x8*)(&Ks[j*16 + tr][((ks*4 + quad) ^ tr7) * 8]);
#pragma unroll
      for (int i = 0; i < 2; i++)
#pragma unroll
        for (int j = 0; j < 4; j++)
          s[i][j] = __builtin_amdgcn_mfma_f32_16x16x32_bf16(qf[i][ks], kf[j], s[i][j], 0, 0, 0);
    }

    // fixed-max softmax: p = exp(score/8); partial l per lane; P -> LDS (b64)
#pragma unroll
    for (int i = 0; i < 2; i++) {
#pragma unroll
      for (int r = 0; r < 4; r++) {
        float p0 = __expf(s[i][0][r] * sc);
        float p1 = __expf(s[i][1][r] * sc);
        float p2 = __expf(s[i][2][r] * sc);
        float p3 = __expf(s[i][3][r] * sc);
        lsum[i][r] += (p0 + p1) + (p2 + p3);
        uint2 w;
        w.x = (__float_as_uint(p0) >> 16) | (__float_as_uint(p1) & 0xffff0000u);
        w.y = (__float_as_uint(p2) >> 16) | (__float_as_uint(p3) & 0xffff0000u);
        *(uint2*)(&Ps[wv][i*16 + quad*4 + r][tr*4]) = w;
      }
    }

    // O += P @ V  (both operands in sigma-permuted key order -> consistent)
#pragma unroll
    for (int ks = 0; ks < 2; ks++) {
      bf16x8 pf[2];
#pragma unroll
      for (int i = 0; i < 2; i++)
        pf[i] = *(const bf16x8*)(&Ps[wv][i*16 + tr][ks*32 + quad*8]);
#pragma unroll
      for (int jd = 0; jd < 4; jd++) {
        bf16x8 vf = *(const bf16x8*)(&Vt[jd*16 + tr][((ks*4 + quad) ^ tr7) * 8]);
#pragma unroll
        for (int i = 0; i < 2; i++)
          o[i][jd] = __builtin_amdgcn_mfma_f32_16x16x32_bf16(pf[i], vf, o[i][jd], 0, 0, 0);
      }
    }
    __syncthreads();
  }

  // finalize: reduce l across the 16 tr lanes, scale, store
#pragma unroll
  for (int i = 0; i < 2; i++) {
#pragma unroll
    for (int r = 0; r < 4; r++) {
      float l = lsum[i][r];
      l += __shfl_xor(l, 1, 64);
      l += __shfl_xor(l, 2, 64);
      l += __shfl_xor(l, 4, 64);
      l += __shfl_xor(l, 8, 64);
      float inv = 1.f / l;
      size_t qrow = rowbase + q0 + wq + i*16 + quad*4 + r;
#pragma unroll
      for (int jd = 0; jd < 4; jd++)
        Ob[qrow * ldo + colbase + jd*16 + tr] = f2bf(o[i][jd][r] * inv);
    }
  }
}

// ---- fused residual-add + LayerNorm, variant A: X fp32 + R bf16 -> Y bf16 ----
__global__ __launch_bounds__(256) void add_ln_a(
    const float* __restrict__ X, const u16* __restrict__ Rr,
    const float* __restrict__ G, const float* __restrict__ Bb,
    u16* __restrict__ Y)
{
  int row = blockIdx.x;
  int tid = threadIdx.x;
  __shared__ float sbuf[4], qbuf[4];
  float4 xv = *(const float4*)(X + (size_t)row * 1024 + tid * 4);
  uint2 ru = *(const uint2*)(Rr + (size_t)row * 1024 + tid * 4);
  const u16* rs = (const u16*)&ru;
  const float* xs = (const float*)&xv;
  float v[4];
  float s = 0.f, q = 0.f;
#pragma unroll
  for (int e = 0; e < 4; e++) {
    float a = xs[e] + bf2f(rs[e]);
    v[e] = a; s += a; q += a * a;
  }
#pragma unroll
  for (int off = 1; off < 64; off <<= 1) {
    s += __shfl_xor(s, off, 64);
    q += __shfl_xor(q, off, 64);
  }
  if ((tid & 63) == 0) { sbuf[tid >> 6] = s; qbuf[tid >> 6] = q; }
  __syncthreads();
  s = sbuf[0] + sbuf[1] + sbuf[2] + sbuf[3];
  q = qbuf[0] + qbuf[1] + qbuf[2] + qbuf[3];
  float mu  = s * (1.f / 1024.f);
  float var = q * (1.f / 1024.f) - mu * mu;
  float inv = rsqrtf(var + 1e-5f);
#pragma unroll
  for (int e = 0; e < 4; e++) {
    int col = tid * 4 + e;
    float yv = (v[e] - mu) * inv * G[col] + Bb[col];
    Y[(size_t)row * 1024 + col] = f2bf(yv);
  }
}

// ---- variant B: X bf16 + R bf16 -> Y fp32 (final output) ----
__global__ __launch_bounds__(256) void add_ln_b(
    const u16* __restrict__ X, const u16* __restrict__ Rr,
    const float* __restrict__ G, const float* __restrict__ Bb,
    float* __restrict__ Y)
{
  int row = blockIdx.x;
  int tid = threadIdx.x;
  __shared__ float sbuf[4], qbuf[4];
  uint2 xu = *(const uint2*)(X  + (size_t)row * 1024 + tid * 4);
  uint2 ru = *(const uint2*)(Rr + (size_t)row * 1024 + tid * 4);
  const u16* xs = (const u16*)&xu;
  const u16* rs = (const u16*)&ru;
  float v[4];
  float s = 0.f, q = 0.f;
#pragma unroll
  for (int e = 0; e < 4; e++) {
    float a = bf2f(xs[e]) + bf2f(rs[e]);
    v[e] = a; s += a; q += a * a;
  }
#pragma unroll
  for (int off = 1; off < 64; off <<= 1) {
    s += __shfl_xor(s, off, 64);
    q += __shfl_xor(q, off, 64);
  }
  if ((tid & 63) == 0) { sbuf[tid >> 6] = s; qbuf[tid >> 6] = q; }
  __syncthreads();
  s = sbuf[0] + sbuf[1] + sbuf[2] + sbuf[3];
  q = qbuf[0] + qbuf[1] + qbuf[2] + qbuf[3];
  float mu  = s * (1.f / 1024.f);
  float var = q * (1.f / 1024.f) - mu * mu;
  float inv = rsqrtf(var + 1e-5f);
  float4 yv;
  float* yp = (float*)&yv;
#pragma unroll
  for (int e = 0; e < 4; e++) {
    int col = tid * 4 + e;
    yp[e] = (v[e] - mu) * inv * G[col] + Bb[col];
  }
  *(float4*)(Y + (size_t)row * 1024 + tid * 4) = yv;
}

extern "C" void kernel_launch(void* const* d_in, const int* in_sizes, int n_in,
                              void* d_out, int out_size, void* d_ws, size_t ws_size,
                              hipStream_t stream) {
  const float* x   = (const float*)d_in[0];
  const float* Wq  = (const float*)d_in[1];
  const float* bq  = (const float*)d_in[2];
  const float* Wk  = (const float*)d_in[3];
  const float* bk  = (const float*)d_in[4];
  const float* Wv  = (const float*)d_in[5];
  const float* bv  = (const float*)d_in[6];
  const float* Wo  = (const float*)d_in[7];
  const float* bo  = (const float*)d_in[8];
  const float* W1  = (const float*)d_in[9];
  const float* b1  = (const float*)d_in[10];
  const float* W2  = (const float*)d_in[11];
  const float* b2  = (const float*)d_in[12];
  const float* g1  = (const float*)d_in[13];
  const float* be1 = (const float*)d_in[14];
  const float* g2  = (const float*)d_in[15];
  const float* be2 = (const float*)d_in[16];
  float* out = (float*)d_out;
  u16* ws  = (u16*)d_ws;

  const int Nrow = 8192, E = 1024, FFd = 4096;
  const size_t M1 = 1048576;
  // workspace (44M u16 = 88 MB peak, proven safe):
  //  [0,8M):   xb -> (after QKV gemm) Vtg -> (after flash) X1
  //  [8,11M):  WqkvT [3072][1024]
  //  [11,12M): WoT
  //  [12,16M): W1T [4096][1024]
  //  [16,20M): W2T [1024][4096]
  //  [20,44M): QKV [8192][3072]; V-slice becomes ctx; region reused as F2
  // d_out (32 MB) doubles as scratch: bqkv fp32 -> AO (u16) -> Hc (u16) -> final fp32
  u16* xb     = ws;
  u16* WqkvT  = ws + 8  * M1;
  u16* WoT    = ws + 11 * M1;
  u16* W1T    = ws + 12 * M1;
  u16* W2T    = ws + 16 * M1;
  u16* QKV    = ws + 20 * M1;
  u16* Vtg    = ws;               // over xb (dead after QKV gemm)
  u16* X1     = ws;               // over Vtg (dead after flash)
  u16* F2     = ws + 20 * M1;     // over QKV (dead after Wo gemm)
  float* bqkv = (float*)d_out;
  u16*  AO    = (u16*)d_out;
  u16*  Hc    = (u16*)d_out;

  dim3 tb(256);
  dim3 tt(32, 8);
  f32_to_bf16<<<dim3(8192), tb, 0, stream>>>(x, xb);
  transpose_f2b<<<dim3(E/32,  E/32),  tt, 0, stream>>>(Wq, WqkvT,        E,   E,   E);
  transpose_f2b<<<dim3(E/32,  E/32),  tt, 0, stream>>>(Wk, WqkvT + 1*M1, E,   E,   E);
  transpose_f2b<<<dim3(E/32,  E/32),  tt, 0, stream>>>(Wv, WqkvT + 2*M1, E,   E,   E);
  transpose_f2b<<<dim3(E/32,  E/32),  tt, 0, stream>>>(Wo, WoT,          E,   E,   E);
  transpose_f2b<<<dim3(FFd/32,E/32),  tt, 0, stream>>>(W1, W1T,          E,   FFd, E);
  transpose_f2b<<<dim3(E/32,  FFd/32),tt, 0, stream>>>(W2, W2T,          FFd, E,   FFd);
  concat_bias<<<dim3(12), tb, 0, stream>>>(bq, bk, bv, bqkv);

  // fused QKV projection: [8192,1024] @ [1024,3072] -> QKV
  gemm_bt<<<dim3(24, Nrow/BM), tb, 0, stream>>>(xb, WqkvT, bqkv, QKV,
                                                3072, E, E, E, 3072, 0, 0);
  // V -> Vtg (transposed + sigma-permuted, per bh)
  transpose_v<<<dim3(32, 64), tb, 0, stream>>>(QKV + 2048, Vtg);
  // flash: ctx written over the V-slice of QKV
  flash_attn<<<dim3(8, 64), dim3(512), 0, stream>>>(QKV, QKV + 1024, Vtg,
                                                    QKV + 2048, 3072, 3072);
  // Wo: ctx (stride 3072) @ WoT -> AO (in d_out)
  gemm_bt<<<dim3(8, Nrow/BM), tb, 0, stream>>>(QKV + 2048, WoT, bo, AO,
                                               E, E, 3072, E, E, 0, 0);
  add_ln_a<<<dim3(Nrow), tb, 0, stream>>>(x, AO, g1, be1, X1);

  // FFN in 2 chunks of 2048 (hidden lives in d_out; F2 accumulates in ws)
  for (int c = 0; c < 2; c++) {
    gemm_bt<<<dim3(16, Nrow/BM), tb, 0, stream>>>(
        X1, W1T + (size_t)c * 2048 * E, b1 + c * 2048, Hc,
        2048, E, E, E, 2048, 1, 0);
    gemm_bt<<<dim3(8, Nrow/BM), tb, 0, stream>>>(
        Hc, W2T + (size_t)c * 2048, (c == 0 ? b2 : (const float*)nullptr), F2,
        E, 2048, 2048, FFd, E, 0, (c == 0 ? 0 : 1));
  }

  add_ln_b<<<dim3(Nrow), tb, 0, stream>>>(X1, F2, g2, be2, out);
}